// Round 2
// baseline (1158.834 us; speedup 1.0000x reference)
//
#include <hip/hip_runtime.h>
#include <math.h>

// ---------------------------------------------------------------------------
// StageA_GNN: full pipeline
//   enc GEMM -> mlp2 -> gate projections -> [CSR build] -> L x (agg -> upd MLP
//   + LN) -> U=softplus(h@toU) -> mu = exp(clip(log lib + log(U@W^T) + alpha
//   + bcorr))
// All fp32. CSR by dst built per call (no atomics in hot loops).
// ---------------------------------------------------------------------------

static __device__ __forceinline__ float sigmoidf_fast(float x){
  return __builtin_amdgcn_rcpf(1.f + __expf(-x));
}
static __device__ __forceinline__ float softplusf_dev(float x){
  return (x > 20.f) ? x : log1pf(__expf(x));
}

// ---------------- prep kernels ----------------
__global__ void k_prep_node(const float* __restrict__ rho_raw, const float* __restrict__ lib,
                            float* __restrict__ rho, float* __restrict__ loglib, int N){
  int i = blockIdx.x*256 + threadIdx.x;
  if (i < N){
    rho[i]    = sigmoidf_fast(rho_raw[i]);
    loglib[i] = __logf(fmaxf(lib[i], 1e-8f));
  }
}

__global__ void k_prep_W(const float* __restrict__ W_raw, float* __restrict__ WT, int C, int K){
  int i = blockIdx.x*256 + threadIdx.x;
  if (i < C*K){
    int k = i / C, c = i - k*C;
    WT[i] = softplusf_dev(W_raw[c*K + k]);   // WT[k][c] = softplus(W[c][k])
  }
}

__global__ void k_prep_bcorr(const float* __restrict__ P, const float* __restrict__ Q,
                             float* __restrict__ bcorr, int S, int R, int C){
  __shared__ float pm[64];
  int t = threadIdx.x;
  if (t < R){
    float s = 0.f;
    for (int i = 0; i < S; ++i) s += P[i*R + t];
    pm[t] = s / (float)S;
  }
  __syncthreads();
  for (int c = t; c < C; c += 256){
    for (int s8 = 0; s8 < S; ++s8){
      float a = 0.f;
      for (int r = 0; r < R; ++r) a += (P[s8*R + r] - pm[r]) * Q[c*R + r];
      bcorr[s8*C + c] = a;
    }
  }
}

// ---------------- CSR build ----------------
__global__ void k_hist(const int* __restrict__ dst, int* __restrict__ cnt, int E){
  int i = blockIdx.x*256 + threadIdx.x;
  if (i < E) atomicAdd(&cnt[dst[i]], 1);
}

__global__ void k_scan1(const int* __restrict__ cnt, int* __restrict__ offs,
                        int* __restrict__ blksum, int N){
  __shared__ int s[1024];
  int t = threadIdx.x;
  int i = blockIdx.x*1024 + t;
  int v = (i < N) ? cnt[i] : 0;
  s[t] = v;
  __syncthreads();
  for (int off = 1; off < 1024; off <<= 1){
    int a = (t >= off) ? s[t-off] : 0;
    __syncthreads();
    s[t] += a;
    __syncthreads();
  }
  if (i < N) offs[i] = s[t] - v;          // block-local exclusive
  if (t == 1023) blksum[blockIdx.x] = s[t];
}

__global__ void k_scan2(int* __restrict__ blksum, int nblk){
  if (threadIdx.x == 0 && blockIdx.x == 0){
    int run = 0;
    for (int i = 0; i < nblk; ++i){ int t = blksum[i]; blksum[i] = run; run += t; }
  }
}

__global__ void k_scan3(int* __restrict__ offs, const int* __restrict__ blksum, int N, int E){
  int i = blockIdx.x*256 + threadIdx.x;
  if (i < N) offs[i] += blksum[i >> 10];
  else if (i == N) offs[N] = E;
}

__global__ void k_fill(const int* __restrict__ src, const int* __restrict__ dst,
                       const float* __restrict__ base_w, const float* __restrict__ dist,
                       const float* __restrict__ rho,
                       const int* __restrict__ offs, int* __restrict__ fill,
                       float4* __restrict__ csr4, int E){
  int i = blockIdx.x*256 + threadIdx.x;
  if (i < E){
    int d = dst[i];
    int p = offs[d] + atomicAdd(&fill[d], 1);
    int s = src[i];
    csr4[p] = make_float4(__int_as_float(s), dist[i], base_w[i]*rho[s], 0.f);
  }
}

// ---------------- encoder layer 1: h1 = relu(X @ W1 + b1) ----------------
// X: (N,C) fp32, W1: (C,64). 64 rows/block, 256 threads (4 waves).
// lane <-> row, wave <-> 16-col group (wave-uniform via readfirstlane so W
// reads become s_load through the scalar cache — zero LDS traffic for W).
// Per k per lane: 1 LDS float -> 16 FMAs (LDS demand ~31% of VALU).
// Xs transposed [k][row ^ ((5k)&63)]: conflict-free reads, ~2-way writes.
__global__ __launch_bounds__(256) void k_enc1(const float* __restrict__ X,
                                              const float* __restrict__ W1,
                                              const float* __restrict__ b1,
                                              float* __restrict__ h1, int N, int C){
  __shared__ float Xs[40*64];
  int tid = threadIdx.x;
  int lane = tid & 63;
  int cg4 = __builtin_amdgcn_readfirstlane((tid >> 6) & 3) * 16;  // col base, wave-uniform
  int row0 = blockIdx.x*64;
  int myrow = row0 + lane;

  // X loader: 64 rows x 40 k = 640 float4 slots; q = tid + i*256
  int lr[3], lk[3]; bool lok[3];
  const float* lg[3];
  #pragma unroll
  for (int i = 0; i < 3; ++i){
    int q = tid + i*256;
    int r = q/10, kq = q - r*10;
    lr[i] = r; lk[i] = kq;
    bool inb = (q < 640) && ((row0 + r) < N);
    lok[i] = inb;
    lg[i] = X + (size_t)(inb ? (row0 + r) : 0)*C + kq*4;
  }
  float4 xr[3];
  auto loadT = [&](int k0){
    #pragma unroll
    for (int i = 0; i < 3; ++i)
      xr[i] = lok[i] ? *(const float4*)(lg[i] + k0) : make_float4(0.f,0.f,0.f,0.f);
  };
  auto storeT = [&](){
    #pragma unroll
    for (int i = 0; i < 3; ++i){
      if (i < 2 || tid < 128){
        int kq = lk[i], r = lr[i];
        #pragma unroll
        for (int e = 0; e < 4; ++e){
          int k = kq*4 + e;
          Xs[k*64 + (r ^ ((5*k) & 63))] = (&xr[i].x)[e];
        }
      }
    }
  };

  float acc[16];
  #pragma unroll
  for (int c = 0; c < 16; ++c) acc[c] = 0.f;

  loadT(0); storeT(); __syncthreads();
  const int nt = C/40;                  // 25
  const float* wb = W1 + cg4;
  for (int t = 0; t < nt; ++t){
    if (t+1 < nt) loadT((t+1)*40);      // prefetch hides under FMA phase
    #pragma unroll 4
    for (int k = 0; k < 40; ++k){
      float xv = Xs[k*64 + (lane ^ ((5*k) & 63))];
      const float* wp = wb + (size_t)(t*40 + k)*64;   // wave-uniform -> s_load
      float4 w0 = *(const float4*)(wp);
      float4 w1 = *(const float4*)(wp + 4);
      float4 w2 = *(const float4*)(wp + 8);
      float4 w3 = *(const float4*)(wp + 12);
      acc[ 0] = fmaf(xv, w0.x, acc[ 0]);
      acc[ 1] = fmaf(xv, w0.y, acc[ 1]);
      acc[ 2] = fmaf(xv, w0.z, acc[ 2]);
      acc[ 3] = fmaf(xv, w0.w, acc[ 3]);
      acc[ 4] = fmaf(xv, w1.x, acc[ 4]);
      acc[ 5] = fmaf(xv, w1.y, acc[ 5]);
      acc[ 6] = fmaf(xv, w1.z, acc[ 6]);
      acc[ 7] = fmaf(xv, w1.w, acc[ 7]);
      acc[ 8] = fmaf(xv, w2.x, acc[ 8]);
      acc[ 9] = fmaf(xv, w2.y, acc[ 9]);
      acc[10] = fmaf(xv, w2.z, acc[10]);
      acc[11] = fmaf(xv, w2.w, acc[11]);
      acc[12] = fmaf(xv, w3.x, acc[12]);
      acc[13] = fmaf(xv, w3.y, acc[13]);
      acc[14] = fmaf(xv, w3.z, acc[14]);
      acc[15] = fmaf(xv, w3.w, acc[15]);
    }
    __syncthreads();
    if (t+1 < nt){ storeT(); __syncthreads(); }
  }

  if (myrow < N){
    float* op = h1 + (size_t)myrow*64 + cg4;
    #pragma unroll
    for (int c4 = 0; c4 < 4; ++c4){
      float4 bv = *(const float4*)(b1 + cg4 + c4*4);
      float4 o;
      o.x = fmaxf(acc[c4*4+0] + bv.x, 0.f);
      o.y = fmaxf(acc[c4*4+1] + bv.y, 0.f);
      o.z = fmaxf(acc[c4*4+2] + bv.z, 0.f);
      o.w = fmaxf(acc[c4*4+3] + bv.w, 0.f);
      *(float4*)(op + c4*4) = o;
    }
  }
}

// ---------------- small GEMM: Y = epi(X(N,64) @ W(64,CO) + bias) ----------
// EPI: 0=none 1=relu 2=layernorm(residual HP) 3=softplus
template<int CO, int EPI>
__global__ __launch_bounds__(256) void k_small_gemm(
    const float* __restrict__ X, int xstride, int xoff,
    const float* __restrict__ W, const float* __restrict__ bias,
    float* __restrict__ Y, int ystride, int yoff,
    const float* __restrict__ HP, int hpstride, int hpoff,
    const float* __restrict__ lng, const float* __restrict__ lnb,
    int nrows){
  constexpr int CPT = CO/16;
  __shared__ float Xs[64*68];
  __shared__ float Ws[64*CO];
  int tid = threadIdx.x;
  int row0 = blockIdx.x*64;
  for (int q = tid; q < 1024; q += 256){
    int r = q >> 4, kq = q & 15;
    int row = row0 + r;
    float4 v = make_float4(0.f,0.f,0.f,0.f);
    if (row < nrows) v = *(const float4*)(X + (size_t)row*xstride + xoff + kq*4);
    *(float4*)(Xs + r*68 + kq*4) = v;
  }
  for (int i = tid; i < 64*CO; i += 256) Ws[i] = W[i];
  __syncthreads();
  int tx = tid & 15, ty = tid >> 4;
  int colbase = tx*CPT;
  float acc[4][CPT];
  #pragma unroll
  for (int p = 0; p < 4; ++p)
    #pragma unroll
    for (int c = 0; c < CPT; ++c) acc[p][c] = 0.f;
  #pragma unroll 8
  for (int k = 0; k < 64; ++k){
    float wv[CPT];
    if constexpr (CPT == 4){
      float4 t = *(const float4*)(Ws + k*CO + colbase);
      wv[0]=t.x; wv[1]=t.y; wv[2]=t.z; wv[3]=t.w;
    } else {
      float2 t = *(const float2*)(Ws + k*CO + colbase);
      wv[0]=t.x; wv[1]=t.y;
    }
    #pragma unroll
    for (int p = 0; p < 4; ++p){
      float x = Xs[(ty*4 + p)*68 + k];
      #pragma unroll
      for (int c = 0; c < CPT; ++c) acc[p][c] = fmaf(x, wv[c], acc[p][c]);
    }
  }
  float bv[CPT];
  #pragma unroll
  for (int c = 0; c < CPT; ++c) bv[c] = bias ? bias[colbase + c] : 0.f;

  if constexpr (EPI == 2){
    // layernorm(h + u)*g + b ; CO must be 64
    float lg[4], lb[4];
    #pragma unroll
    for (int c = 0; c < 4; ++c){ lg[c] = lng[colbase + c]; lb[c] = lnb[colbase + c]; }
    float hn[4][4];
    #pragma unroll
    for (int p = 0; p < 4; ++p){
      int row = row0 + ty*4 + p;
      #pragma unroll
      for (int c = 0; c < 4; ++c){
        float h = (row < nrows) ? HP[(size_t)row*hpstride + hpoff + colbase + c] : 0.f;
        hn[p][c] = h + acc[p][c] + bv[c];
      }
    }
    float rs[4], vs[4];
    #pragma unroll
    for (int p = 0; p < 4; ++p) rs[p] = hn[p][0]+hn[p][1]+hn[p][2]+hn[p][3];
    #pragma unroll
    for (int m = 8; m >= 1; m >>= 1)
      #pragma unroll
      for (int p = 0; p < 4; ++p) rs[p] += __shfl_xor(rs[p], m, 64);
    float mean[4], inv[4];
    #pragma unroll
    for (int p = 0; p < 4; ++p) mean[p] = rs[p] * 0.015625f;
    #pragma unroll
    for (int p = 0; p < 4; ++p){
      float d0 = hn[p][0]-mean[p], d1 = hn[p][1]-mean[p];
      float d2 = hn[p][2]-mean[p], d3 = hn[p][3]-mean[p];
      vs[p] = d0*d0 + d1*d1 + d2*d2 + d3*d3;
    }
    #pragma unroll
    for (int m = 8; m >= 1; m >>= 1)
      #pragma unroll
      for (int p = 0; p < 4; ++p) vs[p] += __shfl_xor(vs[p], m, 64);
    #pragma unroll
    for (int p = 0; p < 4; ++p) inv[p] = 1.f / sqrtf(vs[p]*0.015625f + 1e-5f);
    #pragma unroll
    for (int p = 0; p < 4; ++p){
      int row = row0 + ty*4 + p;
      if (row < nrows){
        float o0 = fmaf(lg[0], (hn[p][0]-mean[p])*inv[p], lb[0]);
        float o1 = fmaf(lg[1], (hn[p][1]-mean[p])*inv[p], lb[1]);
        float o2 = fmaf(lg[2], (hn[p][2]-mean[p])*inv[p], lb[2]);
        float o3 = fmaf(lg[3], (hn[p][3]-mean[p])*inv[p], lb[3]);
        *(float4*)(Y + (size_t)row*ystride + yoff + colbase) = make_float4(o0,o1,o2,o3);
      }
    }
  } else {
    #pragma unroll
    for (int p = 0; p < 4; ++p){
      int row = row0 + ty*4 + p;
      if (row < nrows){
        float o[CPT];
        #pragma unroll
        for (int c = 0; c < CPT; ++c){
          float v = acc[p][c] + bv[c];
          if constexpr (EPI == 1) v = fmaxf(v, 0.f);
          if constexpr (EPI == 3) v = softplusf_dev(v);
          o[c] = v;
        }
        if constexpr (CPT == 4)
          *(float4*)(Y + (size_t)row*ystride + yoff + colbase) = make_float4(o[0],o[1],o[2],o[3]);
        else
          *(float2*)(Y + (size_t)row*ystride + yoff + colbase) = make_float2(o[0],o[1]);
      }
    }
  }
}

// ---------------- aggregation: neigh = (sum_e w*h[src]) / (sum_e w + eps) --
// wave per node; lane = channel. pk row: [a(64) | h(64)].
__global__ __launch_bounds__(256) void k_agg(
    const float* __restrict__ pk, const float* __restrict__ bbuf,
    const float* __restrict__ rho, const float4* __restrict__ csr4,
    const int* __restrict__ offs,
    const float* __restrict__ gw1, const float* __restrict__ gb1,
    const float* __restrict__ gw2, const float* __restrict__ gb2,
    float* __restrict__ neigh, int N){
  int tid = threadIdx.x;
  int j = tid & 63;
  int v = blockIdx.x*4 + (tid >> 6);
  if (v >= N) return;
  float gcj  = gw1[128*64 + j];      // dist row of gate_w1
  float gw2j = gw2[j];
  float bb   = bbuf[(size_t)v*64 + j] + gb1[j];
  float gb2v = gb2[0];
  float rhov = rho[v];
  int beg = offs[v], end = offs[v+1];
  float acc = 0.f, deg = 0.f;
  for (int i = beg; i < end; ++i){
    float4 e = csr4[i];
    int s = __float_as_int(e.x);
    const float* ps = pk + (size_t)s*128;
    float av = ps[j];
    float hv = ps[64 + j];
    float t = fmaxf(fmaf(e.y, gcj, av + bb), 0.f) * gw2j;
    t += __shfl_xor(t, 32, 64);
    t += __shfl_xor(t, 16, 64);
    t += __shfl_xor(t,  8, 64);
    t += __shfl_xor(t,  4, 64);
    t += __shfl_xor(t,  2, 64);
    t += __shfl_xor(t,  1, 64);
    float gate = sigmoidf_fast(t + gb2v);
    float wgt = gate * e.z * rhov;   // e.z = base_w*rho[src]
    acc = fmaf(wgt, hv, acc);
    deg += wgt;
  }
  neigh[(size_t)v*64 + j] = acc * __builtin_amdgcn_rcpf(deg + 1e-8f);
}

// ---------------- final: mu = exp(clip(loglib + log(U@W^T) + alpha + bcorr))
__global__ __launch_bounds__(256) void k_final(
    const float* __restrict__ U, const float* __restrict__ WT,
    const float* __restrict__ alpha, const float* __restrict__ bcorr,
    const float* __restrict__ loglib, const int* __restrict__ sid,
    float* __restrict__ out, int N, int C, int npb){
  int c = blockIdx.x*256 + threadIdx.x;
  bool active = (c < C);
  int cc = active ? c : (C-1);
  float wreg[32];
  #pragma unroll
  for (int k = 0; k < 32; ++k) wreg[k] = WT[k*C + cc];
  float al = alpha[cc];
  int n0 = blockIdx.y * npb;
  int n1 = min(n0 + npb, N);
  for (int n = n0; n < n1; ++n){
    int sd   = sid[n];        // wave-uniform -> scalar loads
    float ll = loglib[n];
    const float* Ur = U + (size_t)n*32;
    float dot = 0.f;
    #pragma unroll
    for (int k = 0; k < 32; ++k) dot = fmaf(Ur[k], wreg[k], dot);
    float lm = ll + __logf(fmaxf(dot, 1e-8f)) + al + bcorr[sd*C + cc];
    lm = fminf(fmaxf(lm, -20.f), 20.f);
    if (active) out[(size_t)n*C + c] = __expf(lm);
  }
}

// ---------------------------------------------------------------------------
extern "C" void kernel_launch(void* const* d_in, const int* in_sizes, int n_in,
                              void* d_out, int out_size, void* d_ws, size_t ws_size,
                              hipStream_t stream){
  const float* x_common = (const float*)d_in[0];
  const int*   src      = (const int*)  d_in[1];
  const int*   dst      = (const int*)  d_in[2];
  const float* base_w   = (const float*)d_in[3];
  const float* dist     = (const float*)d_in[4];
  const float* lib      = (const float*)d_in[5];
  const int*   sid      = (const int*)  d_in[6];
  const float* enc_w1   = (const float*)d_in[7];
  const float* enc_b1   = (const float*)d_in[8];
  const float* enc_w2   = (const float*)d_in[9];
  const float* enc_b2   = (const float*)d_in[10];
  const float* upd_w1   = (const float*)d_in[11];
  const float* upd_b1   = (const float*)d_in[12];
  const float* upd_w2   = (const float*)d_in[13];
  const float* upd_b2   = (const float*)d_in[14];
  const float* ln_g     = (const float*)d_in[15];
  const float* ln_b     = (const float*)d_in[16];
  const float* gate_w1  = (const float*)d_in[17];
  const float* gate_b1  = (const float*)d_in[18];
  const float* gate_w2  = (const float*)d_in[19];
  const float* gate_b2  = (const float*)d_in[20];
  const float* rho_raw  = (const float*)d_in[21];
  const float* toU_w    = (const float*)d_in[22];
  const float* toU_b    = (const float*)d_in[23];
  const float* W_raw    = (const float*)d_in[24];
  const float* alpha    = (const float*)d_in[25];
  const float* P        = (const float*)d_in[26];
  const float* Q        = (const float*)d_in[27];

  const int N = in_sizes[5];            // 50000
  const int E = in_sizes[1];            // 800000
  const int C = in_sizes[25];           // 1000
  const int K = in_sizes[23];           // 32
  const int R = in_sizes[27] / C;       // 16
  const int S = in_sizes[26] / R;       // 8
  const int L = in_sizes[15] / 64;      // 2

  float* w = (float*)d_ws;
  size_t o = 0;
  auto alloc = [&](size_t n)->float*{ float* p = w + o; o += (n + 63) & ~((size_t)63); return p; };
  float*  pkA   = alloc((size_t)N*128);   // [a | h] packed per node
  float*  pkB   = alloc((size_t)N*128);
  float*  bbuf  = alloc((size_t)N*64);
  float*  tbuf  = alloc((size_t)N*64);    // h1, later update-MLP hidden
  float*  neigh = alloc((size_t)N*64);
  float*  Ubuf  = alloc((size_t)N*32);
  float*  rho   = alloc((size_t)N);
  float*  loglib= alloc((size_t)N);
  float*  WT    = alloc((size_t)K*C);
  float*  bcorr = alloc((size_t)S*C);
  float4* csr4  = (float4*)alloc((size_t)E*4);
  int*    cnt   = (int*)alloc((size_t)N);
  int*    offs  = (int*)alloc((size_t)N + 64);
  int*    fillc = (int*)alloc((size_t)N);
  int*    blksum= (int*)alloc(256);

  hipMemsetAsync(cnt,   0, sizeof(int)*(size_t)N, stream);
  hipMemsetAsync(fillc, 0, sizeof(int)*(size_t)N, stream);

  // prep
  k_prep_node<<<(N+255)/256,256,0,stream>>>(rho_raw, lib, rho, loglib, N);
  k_prep_W<<<(K*C+255)/256,256,0,stream>>>(W_raw, WT, C, K);
  k_prep_bcorr<<<1,256,0,stream>>>(P, Q, bcorr, S, R, C);

  // CSR by dst
  k_hist<<<(E+255)/256,256,0,stream>>>(dst, cnt, E);
  int nblk = (N+1023)/1024;
  k_scan1<<<nblk,1024,0,stream>>>(cnt, offs, blksum, N);
  k_scan2<<<1,64,0,stream>>>(blksum, nblk);
  k_scan3<<<(N+256)/256,256,0,stream>>>(offs, blksum, N, E);
  k_fill<<<(E+255)/256,256,0,stream>>>(src, dst, base_w, dist, rho, offs, fillc, csr4, E);

  // encoder
  k_enc1<<<(N+63)/64,256,0,stream>>>(x_common, enc_w1, enc_b1, tbuf, N, C);
  int gsm = (N+63)/64;
  // h = relu(h1@enc_w2 + b2) -> pkA.h
  k_small_gemm<64,1><<<gsm,256,0,stream>>>(tbuf,64,0, enc_w2, enc_b2, pkA,128,64,
                                           nullptr,0,0, nullptr,nullptr, N);
  // gate projections: a = h@gw1[0:64], b = h@gw1[64:128]
  k_small_gemm<64,0><<<gsm,256,0,stream>>>(pkA,128,64, gate_w1, nullptr, pkA,128,0,
                                           nullptr,0,0, nullptr,nullptr, N);
  k_small_gemm<64,0><<<gsm,256,0,stream>>>(pkA,128,64, gate_w1+64*64, nullptr, bbuf,64,0,
                                           nullptr,0,0, nullptr,nullptr, N);

  float* cur = pkA; float* nxt = pkB;
  for (int l = 0; l < L; ++l){
    k_agg<<<(N+3)/4,256,0,stream>>>(cur, bbuf, rho, csr4, offs,
                                    gate_w1, gate_b1, gate_w2, gate_b2, neigh, N);
    k_small_gemm<64,1><<<gsm,256,0,stream>>>(neigh,64,0, upd_w1 + (size_t)l*64*64, upd_b1 + l*64,
                                             tbuf,64,0, nullptr,0,0, nullptr,nullptr, N);
    k_small_gemm<64,2><<<gsm,256,0,stream>>>(tbuf,64,0, upd_w2 + (size_t)l*64*64, upd_b2 + l*64,
                                             nxt,128,64, cur,128,64, ln_g + l*64, ln_b + l*64, N);
    if (l + 1 < L){
      k_small_gemm<64,0><<<gsm,256,0,stream>>>(nxt,128,64, gate_w1, nullptr, nxt,128,0,
                                               nullptr,0,0, nullptr,nullptr, N);
      k_small_gemm<64,0><<<gsm,256,0,stream>>>(nxt,128,64, gate_w1+64*64, nullptr, bbuf,64,0,
                                               nullptr,0,0, nullptr,nullptr, N);
    }
    float* t = cur; cur = nxt; nxt = t;
  }

  // U = softplus(h @ toU_w + toU_b)
  k_small_gemm<32,3><<<gsm,256,0,stream>>>(cur,128,64, toU_w, toU_b, Ubuf,32,0,
                                           nullptr,0,0, nullptr,nullptr, N);

  // mu
  dim3 fg((C+255)/256, (N+63)/64);
  k_final<<<fg,256,0,stream>>>(Ubuf, WT, alpha, bcorr, loglib, sid, (float*)d_out, N, C, 64);
}

// Round 3
// 1061.920 us; speedup vs baseline: 1.0913x; 1.0913x over previous
//
#include <hip/hip_runtime.h>
#include <math.h>

// ---------------------------------------------------------------------------
// StageA_GNN: full pipeline
//   enc GEMM (split-K x2 + fixup) -> mlp2 -> gate projections -> [CSR build]
//   -> L x (agg -> upd MLP + LN) -> U=softplus(h@toU) -> mu = exp(clip(...))
// All fp32. CSR by dst built per call (no atomics in hot loops).
// ---------------------------------------------------------------------------

static __device__ __forceinline__ float sigmoidf_fast(float x){
  return __builtin_amdgcn_rcpf(1.f + __expf(-x));
}
static __device__ __forceinline__ float softplusf_dev(float x){
  return (x > 20.f) ? x : log1pf(__expf(x));
}

// ---------------- prep kernels ----------------
__global__ void k_prep_node(const float* __restrict__ rho_raw, const float* __restrict__ lib,
                            float* __restrict__ rho, float* __restrict__ loglib, int N){
  int i = blockIdx.x*256 + threadIdx.x;
  if (i < N){
    rho[i]    = sigmoidf_fast(rho_raw[i]);
    loglib[i] = __logf(fmaxf(lib[i], 1e-8f));
  }
}

__global__ void k_prep_W(const float* __restrict__ W_raw, float* __restrict__ WT, int C, int K){
  int i = blockIdx.x*256 + threadIdx.x;
  if (i < C*K){
    int k = i / C, c = i - k*C;
    WT[i] = softplusf_dev(W_raw[c*K + k]);   // WT[k][c] = softplus(W[c][k])
  }
}

__global__ void k_prep_bcorr(const float* __restrict__ P, const float* __restrict__ Q,
                             float* __restrict__ bcorr, int S, int R, int C){
  __shared__ float pm[64];
  int t = threadIdx.x;
  if (t < R){
    float s = 0.f;
    for (int i = 0; i < S; ++i) s += P[i*R + t];
    pm[t] = s / (float)S;
  }
  __syncthreads();
  for (int c = t; c < C; c += 256){
    for (int s8 = 0; s8 < S; ++s8){
      float a = 0.f;
      for (int r = 0; r < R; ++r) a += (P[s8*R + r] - pm[r]) * Q[c*R + r];
      bcorr[s8*C + c] = a;
    }
  }
}

// ---------------- CSR build ----------------
__global__ void k_hist(const int* __restrict__ dst, int* __restrict__ cnt, int E){
  int i = blockIdx.x*256 + threadIdx.x;
  if (i < E) atomicAdd(&cnt[dst[i]], 1);
}

__global__ void k_scan1(const int* __restrict__ cnt, int* __restrict__ offs,
                        int* __restrict__ blksum, int N){
  __shared__ int s[1024];
  int t = threadIdx.x;
  int i = blockIdx.x*1024 + t;
  int v = (i < N) ? cnt[i] : 0;
  s[t] = v;
  __syncthreads();
  for (int off = 1; off < 1024; off <<= 1){
    int a = (t >= off) ? s[t-off] : 0;
    __syncthreads();
    s[t] += a;
    __syncthreads();
  }
  if (i < N) offs[i] = s[t] - v;          // block-local exclusive
  if (t == 1023) blksum[blockIdx.x] = s[t];
}

__global__ void k_scan2(int* __restrict__ blksum, int nblk){
  if (threadIdx.x == 0 && blockIdx.x == 0){
    int run = 0;
    for (int i = 0; i < nblk; ++i){ int t = blksum[i]; blksum[i] = run; run += t; }
  }
}

__global__ void k_scan3(int* __restrict__ offs, const int* __restrict__ blksum, int N, int E){
  int i = blockIdx.x*256 + threadIdx.x;
  if (i < N) offs[i] += blksum[i >> 10];
  else if (i == N) offs[N] = E;
}

__global__ void k_fill(const int* __restrict__ src, const int* __restrict__ dst,
                       const float* __restrict__ base_w, const float* __restrict__ dist,
                       const float* __restrict__ rho,
                       const int* __restrict__ offs, int* __restrict__ fill,
                       float4* __restrict__ csr4, int E){
  int i = blockIdx.x*256 + threadIdx.x;
  if (i < E){
    int d = dst[i];
    int p = offs[d] + atomicAdd(&fill[d], 1);
    int s = src[i];
    csr4[p] = make_float4(__int_as_float(s), dist[i], base_w[i]*rho[s], 0.f);
  }
}

// ---------------- encoder layer 1 (split-K): part = X @ W1 ----------------
// X: (N,C) fp32, W1: (C,64). 128 rows/block, 256 threads (4 waves), BK=32.
// Thread grid 16x16: 8 rows x 4 cols per thread (32 acc). Per k:
// 2 ds_read_b128 (X, transposed [k][row] stride 132) + 1 ds_read_b128 (W,
// [k][68]) -> 32 FMA. Split-K x2 via blockIdx.y -> 782 blocks = 3 blk/CU
// = 3 waves/SIMD (latency hiding). Reg-prefetch of next tile before compute.
__global__ __launch_bounds__(256) void k_enc1(const float* __restrict__ X,
                                              const float* __restrict__ W1,
                                              float* __restrict__ part, int partstride,
                                              int N, int C, int khalf){
  __shared__ float Xs[32*132];
  __shared__ float Ws[32*68];
  int tid = threadIdx.x;
  int row0 = blockIdx.x*128;
  int kbeg = blockIdx.y * khalf;
  int kend = min(kbeg + khalf, C);
  part += (size_t)blockIdx.y * partstride;

  int tx4 = (tid & 15)*4;     // col base
  int ty8 = (tid >> 4)*8;     // row base

  // X staging coords: row sr (0..127), k-half skh (0 or 16)
  int sr  = tid >> 1;
  int skh = (tid & 1)*16;
  bool rok = (row0 + sr) < N;
  const float* xrow = X + (size_t)(rok ? (row0 + sr) : 0)*C;
  // W staging coords: kk = tid&31, cc = (tid>>5)*8  (4-way write conflict ok)
  int wkk = tid & 31;
  int wcc = (tid >> 5)*8;

  float4 xr[4]; float4 wr[2];
  auto loadT = [&](int k0){
    #pragma unroll
    for (int j = 0; j < 4; ++j){
      int k = k0 + skh + j*4;
      xr[j] = (rok && k < kend) ? *(const float4*)(xrow + k) : make_float4(0.f,0.f,0.f,0.f);
    }
    int k = k0 + wkk;
    if (k < kend){
      const float* wp = W1 + (size_t)k*64 + wcc;
      wr[0] = *(const float4*)(wp);
      wr[1] = *(const float4*)(wp + 4);
    } else {
      wr[0] = make_float4(0.f,0.f,0.f,0.f);
      wr[1] = make_float4(0.f,0.f,0.f,0.f);
    }
  };
  auto storeT = [&](){
    #pragma unroll
    for (int j = 0; j < 4; ++j){
      #pragma unroll
      for (int e = 0; e < 4; ++e){
        int k = skh + j*4 + e;
        Xs[k*132 + sr] = (&xr[j].x)[e];
      }
    }
    *(float4*)(Ws + wkk*68 + wcc)     = wr[0];
    *(float4*)(Ws + wkk*68 + wcc + 4) = wr[1];
  };

  float acc[8][4];
  #pragma unroll
  for (int p = 0; p < 8; ++p){
    acc[p][0]=0.f; acc[p][1]=0.f; acc[p][2]=0.f; acc[p][3]=0.f;
  }

  loadT(kbeg); storeT(); __syncthreads();
  int nt = (kend - kbeg + 31) >> 5;
  for (int t = 0; t < nt; ++t){
    if (t+1 < nt) loadT(kbeg + (t+1)*32);   // prefetch hides under FMA phase
    #pragma unroll 4
    for (int k = 0; k < 32; ++k){
      float4 xa = *(const float4*)(Xs + k*132 + ty8);
      float4 xb = *(const float4*)(Xs + k*132 + ty8 + 4);
      float4 wv = *(const float4*)(Ws + k*68 + tx4);
      float xv[8] = {xa.x,xa.y,xa.z,xa.w,xb.x,xb.y,xb.z,xb.w};
      #pragma unroll
      for (int p = 0; p < 8; ++p){
        acc[p][0] = fmaf(xv[p], wv.x, acc[p][0]);
        acc[p][1] = fmaf(xv[p], wv.y, acc[p][1]);
        acc[p][2] = fmaf(xv[p], wv.z, acc[p][2]);
        acc[p][3] = fmaf(xv[p], wv.w, acc[p][3]);
      }
    }
    __syncthreads();
    if (t+1 < nt){ storeT(); __syncthreads(); }
  }

  #pragma unroll
  for (int p = 0; p < 8; ++p){
    int row = row0 + ty8 + p;
    if (row < N)
      *(float4*)(part + (size_t)row*64 + tx4) =
          make_float4(acc[p][0], acc[p][1], acc[p][2], acc[p][3]);
  }
}

// fixup: h1 = relu(part0 + part1 + b1)
__global__ __launch_bounds__(256) void k_encfix(const float* __restrict__ p0,
                                                const float* __restrict__ p1,
                                                const float* __restrict__ b1,
                                                float* __restrict__ h1, int total4){
  int i = blockIdx.x*256 + threadIdx.x;
  if (i < total4){
    float4 a = *(const float4*)(p0 + (size_t)i*4);
    float4 b = *(const float4*)(p1 + (size_t)i*4);
    float4 bv = *(const float4*)(b1 + ((i*4) & 63));
    float4 o;
    o.x = fmaxf(a.x + b.x + bv.x, 0.f);
    o.y = fmaxf(a.y + b.y + bv.y, 0.f);
    o.z = fmaxf(a.z + b.z + bv.z, 0.f);
    o.w = fmaxf(a.w + b.w + bv.w, 0.f);
    *(float4*)(h1 + (size_t)i*4) = o;
  }
}

// ---------------- small GEMM: Y = epi(X(N,64) @ W(64,CO) + bias) ----------
// EPI: 0=none 1=relu 2=layernorm(residual HP) 3=softplus
template<int CO, int EPI>
__global__ __launch_bounds__(256) void k_small_gemm(
    const float* __restrict__ X, int xstride, int xoff,
    const float* __restrict__ W, const float* __restrict__ bias,
    float* __restrict__ Y, int ystride, int yoff,
    const float* __restrict__ HP, int hpstride, int hpoff,
    const float* __restrict__ lng, const float* __restrict__ lnb,
    int nrows){
  constexpr int CPT = CO/16;
  __shared__ float Xs[64*68];
  __shared__ float Ws[64*CO];
  int tid = threadIdx.x;
  int row0 = blockIdx.x*64;
  for (int q = tid; q < 1024; q += 256){
    int r = q >> 4, kq = q & 15;
    int row = row0 + r;
    float4 v = make_float4(0.f,0.f,0.f,0.f);
    if (row < nrows) v = *(const float4*)(X + (size_t)row*xstride + xoff + kq*4);
    *(float4*)(Xs + r*68 + kq*4) = v;
  }
  for (int i = tid; i < 64*CO; i += 256) Ws[i] = W[i];
  __syncthreads();
  int tx = tid & 15, ty = tid >> 4;
  int colbase = tx*CPT;
  float acc[4][CPT];
  #pragma unroll
  for (int p = 0; p < 4; ++p)
    #pragma unroll
    for (int c = 0; c < CPT; ++c) acc[p][c] = 0.f;
  #pragma unroll 8
  for (int k = 0; k < 64; ++k){
    float wv[CPT];
    if constexpr (CPT == 4){
      float4 t = *(const float4*)(Ws + k*CO + colbase);
      wv[0]=t.x; wv[1]=t.y; wv[2]=t.z; wv[3]=t.w;
    } else {
      float2 t = *(const float2*)(Ws + k*CO + colbase);
      wv[0]=t.x; wv[1]=t.y;
    }
    #pragma unroll
    for (int p = 0; p < 4; ++p){
      float x = Xs[(ty*4 + p)*68 + k];
      #pragma unroll
      for (int c = 0; c < CPT; ++c) acc[p][c] = fmaf(x, wv[c], acc[p][c]);
    }
  }
  float bv[CPT];
  #pragma unroll
  for (int c = 0; c < CPT; ++c) bv[c] = bias ? bias[colbase + c] : 0.f;

  if constexpr (EPI == 2){
    // layernorm(h + u)*g + b ; CO must be 64
    float lg[4], lb[4];
    #pragma unroll
    for (int c = 0; c < 4; ++c){ lg[c] = lng[colbase + c]; lb[c] = lnb[colbase + c]; }
    float hn[4][4];
    #pragma unroll
    for (int p = 0; p < 4; ++p){
      int row = row0 + ty*4 + p;
      #pragma unroll
      for (int c = 0; c < 4; ++c){
        float h = (row < nrows) ? HP[(size_t)row*hpstride + hpoff + colbase + c] : 0.f;
        hn[p][c] = h + acc[p][c] + bv[c];
      }
    }
    float rs[4], vs[4];
    #pragma unroll
    for (int p = 0; p < 4; ++p) rs[p] = hn[p][0]+hn[p][1]+hn[p][2]+hn[p][3];
    #pragma unroll
    for (int m = 8; m >= 1; m >>= 1)
      #pragma unroll
      for (int p = 0; p < 4; ++p) rs[p] += __shfl_xor(rs[p], m, 64);
    float mean[4], inv[4];
    #pragma unroll
    for (int p = 0; p < 4; ++p) mean[p] = rs[p] * 0.015625f;
    #pragma unroll
    for (int p = 0; p < 4; ++p){
      float d0 = hn[p][0]-mean[p], d1 = hn[p][1]-mean[p];
      float d2 = hn[p][2]-mean[p], d3 = hn[p][3]-mean[p];
      vs[p] = d0*d0 + d1*d1 + d2*d2 + d3*d3;
    }
    #pragma unroll
    for (int m = 8; m >= 1; m >>= 1)
      #pragma unroll
      for (int p = 0; p < 4; ++p) vs[p] += __shfl_xor(vs[p], m, 64);
    #pragma unroll
    for (int p = 0; p < 4; ++p) inv[p] = 1.f / sqrtf(vs[p]*0.015625f + 1e-5f);
    #pragma unroll
    for (int p = 0; p < 4; ++p){
      int row = row0 + ty*4 + p;
      if (row < nrows){
        float o0 = fmaf(lg[0], (hn[p][0]-mean[p])*inv[p], lb[0]);
        float o1 = fmaf(lg[1], (hn[p][1]-mean[p])*inv[p], lb[1]);
        float o2 = fmaf(lg[2], (hn[p][2]-mean[p])*inv[p], lb[2]);
        float o3 = fmaf(lg[3], (hn[p][3]-mean[p])*inv[p], lb[3]);
        *(float4*)(Y + (size_t)row*ystride + yoff + colbase) = make_float4(o0,o1,o2,o3);
      }
    }
  } else {
    #pragma unroll
    for (int p = 0; p < 4; ++p){
      int row = row0 + ty*4 + p;
      if (row < nrows){
        float o[CPT];
        #pragma unroll
        for (int c = 0; c < CPT; ++c){
          float v = acc[p][c] + bv[c];
          if constexpr (EPI == 1) v = fmaxf(v, 0.f);
          if constexpr (EPI == 3) v = softplusf_dev(v);
          o[c] = v;
        }
        if constexpr (CPT == 4)
          *(float4*)(Y + (size_t)row*ystride + yoff + colbase) = make_float4(o[0],o[1],o[2],o[3]);
        else
          *(float2*)(Y + (size_t)row*ystride + yoff + colbase) = make_float2(o[0],o[1]);
      }
    }
  }
}

// ---------------- aggregation: neigh = (sum_e w*h[src]) / (sum_e w + eps) --
// wave per node; lane = channel. pk row: [a(64) | h(64)].
__global__ __launch_bounds__(256) void k_agg(
    const float* __restrict__ pk, const float* __restrict__ bbuf,
    const float* __restrict__ rho, const float4* __restrict__ csr4,
    const int* __restrict__ offs,
    const float* __restrict__ gw1, const float* __restrict__ gb1,
    const float* __restrict__ gw2, const float* __restrict__ gb2,
    float* __restrict__ neigh, int N){
  int tid = threadIdx.x;
  int j = tid & 63;
  int v = blockIdx.x*4 + (tid >> 6);
  if (v >= N) return;
  float gcj  = gw1[128*64 + j];      // dist row of gate_w1
  float gw2j = gw2[j];
  float bb   = bbuf[(size_t)v*64 + j] + gb1[j];
  float gb2v = gb2[0];
  float rhov = rho[v];
  int beg = offs[v], end = offs[v+1];
  float acc = 0.f, deg = 0.f;
  for (int i = beg; i < end; ++i){
    float4 e = csr4[i];
    int s = __float_as_int(e.x);
    const float* ps = pk + (size_t)s*128;
    float av = ps[j];
    float hv = ps[64 + j];
    float t = fmaxf(fmaf(e.y, gcj, av + bb), 0.f) * gw2j;
    t += __shfl_xor(t, 32, 64);
    t += __shfl_xor(t, 16, 64);
    t += __shfl_xor(t,  8, 64);
    t += __shfl_xor(t,  4, 64);
    t += __shfl_xor(t,  2, 64);
    t += __shfl_xor(t,  1, 64);
    float gate = sigmoidf_fast(t + gb2v);
    float wgt = gate * e.z * rhov;   // e.z = base_w*rho[src]
    acc = fmaf(wgt, hv, acc);
    deg += wgt;
  }
  neigh[(size_t)v*64 + j] = acc * __builtin_amdgcn_rcpf(deg + 1e-8f);
}

// ---------------- final: mu = exp(clip(loglib + log(U@W^T) + alpha + bcorr))
__global__ __launch_bounds__(256) void k_final(
    const float* __restrict__ U, const float* __restrict__ WT,
    const float* __restrict__ alpha, const float* __restrict__ bcorr,
    const float* __restrict__ loglib, const int* __restrict__ sid,
    float* __restrict__ out, int N, int C, int npb){
  int c = blockIdx.x*256 + threadIdx.x;
  bool active = (c < C);
  int cc = active ? c : (C-1);
  float wreg[32];
  #pragma unroll
  for (int k = 0; k < 32; ++k) wreg[k] = WT[k*C + cc];
  float al = alpha[cc];
  int n0 = blockIdx.y * npb;
  int n1 = min(n0 + npb, N);
  for (int n = n0; n < n1; ++n){
    int sd   = sid[n];        // wave-uniform -> scalar loads
    float ll = loglib[n];
    const float* Ur = U + (size_t)n*32;
    float dot = 0.f;
    #pragma unroll
    for (int k = 0; k < 32; ++k) dot = fmaf(Ur[k], wreg[k], dot);
    float lm = ll + __logf(fmaxf(dot, 1e-8f)) + al + bcorr[sd*C + cc];
    lm = fminf(fmaxf(lm, -20.f), 20.f);
    if (active) out[(size_t)n*C + c] = __expf(lm);
  }
}

// ---------------------------------------------------------------------------
extern "C" void kernel_launch(void* const* d_in, const int* in_sizes, int n_in,
                              void* d_out, int out_size, void* d_ws, size_t ws_size,
                              hipStream_t stream){
  const float* x_common = (const float*)d_in[0];
  const int*   src      = (const int*)  d_in[1];
  const int*   dst      = (const int*)  d_in[2];
  const float* base_w   = (const float*)d_in[3];
  const float* dist     = (const float*)d_in[4];
  const float* lib      = (const float*)d_in[5];
  const int*   sid      = (const int*)  d_in[6];
  const float* enc_w1   = (const float*)d_in[7];
  const float* enc_b1   = (const float*)d_in[8];
  const float* enc_w2   = (const float*)d_in[9];
  const float* enc_b2   = (const float*)d_in[10];
  const float* upd_w1   = (const float*)d_in[11];
  const float* upd_b1   = (const float*)d_in[12];
  const float* upd_w2   = (const float*)d_in[13];
  const float* upd_b2   = (const float*)d_in[14];
  const float* ln_g     = (const float*)d_in[15];
  const float* ln_b     = (const float*)d_in[16];
  const float* gate_w1  = (const float*)d_in[17];
  const float* gate_b1  = (const float*)d_in[18];
  const float* gate_w2  = (const float*)d_in[19];
  const float* gate_b2  = (const float*)d_in[20];
  const float* rho_raw  = (const float*)d_in[21];
  const float* toU_w    = (const float*)d_in[22];
  const float* toU_b    = (const float*)d_in[23];
  const float* W_raw    = (const float*)d_in[24];
  const float* alpha    = (const float*)d_in[25];
  const float* P        = (const float*)d_in[26];
  const float* Q        = (const float*)d_in[27];

  const int N = in_sizes[5];            // 50000
  const int E = in_sizes[1];            // 800000
  const int C = in_sizes[25];           // 1000
  const int K = in_sizes[23];           // 32
  const int R = in_sizes[27] / C;       // 16
  const int S = in_sizes[26] / R;       // 8
  const int L = in_sizes[15] / 64;      // 2

  float* w = (float*)d_ws;
  size_t o = 0;
  auto alloc = [&](size_t n)->float*{ float* p = w + o; o += (n + 63) & ~((size_t)63); return p; };
  float*  pkA   = alloc((size_t)N*128);   // [a | h] packed per node
  float*  pkB   = alloc((size_t)N*128);
  float*  bbuf  = alloc((size_t)N*64);
  float*  tbuf  = alloc((size_t)N*64);    // h1, later update-MLP hidden
  float*  neigh = alloc((size_t)N*64);
  float*  Ubuf  = alloc((size_t)N*32);
  float*  rho   = alloc((size_t)N);
  float*  loglib= alloc((size_t)N);
  float*  WT    = alloc((size_t)K*C);
  float*  bcorr = alloc((size_t)S*C);
  float4* csr4  = (float4*)alloc((size_t)E*4);
  int*    cnt   = (int*)alloc((size_t)N);
  int*    offs  = (int*)alloc((size_t)N + 64);
  int*    fillc = (int*)alloc((size_t)N);
  int*    blksum= (int*)alloc(256);

  hipMemsetAsync(cnt,   0, sizeof(int)*(size_t)N, stream);
  hipMemsetAsync(fillc, 0, sizeof(int)*(size_t)N, stream);

  // prep
  k_prep_node<<<(N+255)/256,256,0,stream>>>(rho_raw, lib, rho, loglib, N);
  k_prep_W<<<(K*C+255)/256,256,0,stream>>>(W_raw, WT, C, K);
  k_prep_bcorr<<<1,256,0,stream>>>(P, Q, bcorr, S, R, C);

  // CSR by dst
  k_hist<<<(E+255)/256,256,0,stream>>>(dst, cnt, E);
  int nblk = (N+1023)/1024;
  k_scan1<<<nblk,1024,0,stream>>>(cnt, offs, blksum, N);
  k_scan2<<<1,64,0,stream>>>(blksum, nblk);
  k_scan3<<<(N+256)/256,256,0,stream>>>(offs, blksum, N, E);
  k_fill<<<(E+255)/256,256,0,stream>>>(src, dst, base_w, dist, rho, offs, fillc, csr4, E);

  // encoder layer 1: split-K x2 into pkB halves, then fixup into tbuf
  int khalf = ((C + 1)/2 + 3) & ~3;     // 500, float4-aligned
  dim3 eg((N + 127)/128, 2);
  k_enc1<<<eg,256,0,stream>>>(x_common, enc_w1, pkB, N*64, N, C, khalf);
  int total4 = (N*64)/4;
  k_encfix<<<(total4+255)/256,256,0,stream>>>(pkB, pkB + (size_t)N*64, enc_b1, tbuf, total4);

  int gsm = (N+63)/64;
  // h = relu(h1@enc_w2 + b2) -> pkA.h
  k_small_gemm<64,1><<<gsm,256,0,stream>>>(tbuf,64,0, enc_w2, enc_b2, pkA,128,64,
                                           nullptr,0,0, nullptr,nullptr, N);
  // gate projections: a = h@gw1[0:64], b = h@gw1[64:128]
  k_small_gemm<64,0><<<gsm,256,0,stream>>>(pkA,128,64, gate_w1, nullptr, pkA,128,0,
                                           nullptr,0,0, nullptr,nullptr, N);
  k_small_gemm<64,0><<<gsm,256,0,stream>>>(pkA,128,64, gate_w1+64*64, nullptr, bbuf,64,0,
                                           nullptr,0,0, nullptr,nullptr, N);

  float* cur = pkA; float* nxt = pkB;
  for (int l = 0; l < L; ++l){
    k_agg<<<(N+3)/4,256,0,stream>>>(cur, bbuf, rho, csr4, offs,
                                    gate_w1, gate_b1, gate_w2, gate_b2, neigh, N);
    k_small_gemm<64,1><<<gsm,256,0,stream>>>(neigh,64,0, upd_w1 + (size_t)l*64*64, upd_b1 + l*64,
                                             tbuf,64,0, nullptr,0,0, nullptr,nullptr, N);
    k_small_gemm<64,2><<<gsm,256,0,stream>>>(tbuf,64,0, upd_w2 + (size_t)l*64*64, upd_b2 + l*64,
                                             nxt,128,64, cur,128,64, ln_g + l*64, ln_b + l*64, N);
    if (l + 1 < L){
      k_small_gemm<64,0><<<gsm,256,0,stream>>>(nxt,128,64, gate_w1, nullptr, nxt,128,0,
                                               nullptr,0,0, nullptr,nullptr, N);
      k_small_gemm<64,0><<<gsm,256,0,stream>>>(nxt,128,64, gate_w1+64*64, nullptr, bbuf,64,0,
                                               nullptr,0,0, nullptr,nullptr, N);
    }
    float* t = cur; cur = nxt; nxt = t;
  }

  // U = softplus(h @ toU_w + toU_b)
  k_small_gemm<32,3><<<gsm,256,0,stream>>>(cur,128,64, toU_w, toU_b, Ubuf,32,0,
                                           nullptr,0,0, nullptr,nullptr, N);

  // mu
  dim3 fg((C+255)/256, (N+63)/64);
  k_final<<<fg,256,0,stream>>>(Ubuf, WT, alpha, bcorr, loglib, sid, (float*)d_out, N, C, 64);
}

// Round 4
// 989.882 us; speedup vs baseline: 1.1707x; 1.0728x over previous
//
#include <hip/hip_runtime.h>
#include <math.h>

// ---------------------------------------------------------------------------
// StageA_GNN: full pipeline
//   enc GEMM (split-K x4 + fixup) -> mlp2 -> fused gate projections ->
//   [CSR build] -> L x (agg -> upd MLP + LN) -> U=softplus(h@toU) ->
//   mu = exp(clip(log lib + log(U@W^T) + alpha + bcorr))
// All fp32. CSR by dst built per call (no atomics in hot loops).
// ---------------------------------------------------------------------------

static __device__ __forceinline__ float sigmoidf_fast(float x){
  return __builtin_amdgcn_rcpf(1.f + __expf(-x));
}
static __device__ __forceinline__ float softplusf_dev(float x){
  return (x > 20.f) ? x : log1pf(__expf(x));
}
static __device__ __forceinline__ void gload_lds16(const void* g, void* l){
  __builtin_amdgcn_global_load_lds(
      (const __attribute__((address_space(1))) void*)g,
      (__attribute__((address_space(3))) void*)l, 16, 0, 0);
}

// ---------------- prep kernels ----------------
__global__ void k_prep_node(const float* __restrict__ rho_raw, const float* __restrict__ lib,
                            float* __restrict__ rho, float* __restrict__ loglib, int N){
  int i = blockIdx.x*256 + threadIdx.x;
  if (i < N){
    rho[i]    = sigmoidf_fast(rho_raw[i]);
    loglib[i] = __logf(fmaxf(lib[i], 1e-8f));
  }
}

__global__ void k_prep_W(const float* __restrict__ W_raw, float* __restrict__ WT, int C, int K){
  int i = blockIdx.x*256 + threadIdx.x;
  if (i < C*K){
    int k = i / C, c = i - k*C;
    WT[i] = softplusf_dev(W_raw[c*K + k]);   // WT[k][c] = softplus(W[c][k])
  }
}

__global__ void k_prep_bcorr(const float* __restrict__ P, const float* __restrict__ Q,
                             float* __restrict__ bcorr, int S, int R, int C){
  __shared__ float pm[64];
  int t = threadIdx.x;
  if (t < R){
    float s = 0.f;
    for (int i = 0; i < S; ++i) s += P[i*R + t];
    pm[t] = s / (float)S;
  }
  __syncthreads();
  for (int c = t; c < C; c += 256){
    for (int s8 = 0; s8 < S; ++s8){
      float a = 0.f;
      for (int r = 0; r < R; ++r) a += (P[s8*R + r] - pm[r]) * Q[c*R + r];
      bcorr[s8*C + c] = a;
    }
  }
}

// ---------------- CSR build ----------------
__global__ void k_hist(const int* __restrict__ dst, int* __restrict__ cnt, int E){
  int i = blockIdx.x*256 + threadIdx.x;
  if (i < E) atomicAdd(&cnt[dst[i]], 1);
}

__global__ void k_scan1(const int* __restrict__ cnt, int* __restrict__ offs,
                        int* __restrict__ blksum, int N){
  __shared__ int s[1024];
  int t = threadIdx.x;
  int i = blockIdx.x*1024 + t;
  int v = (i < N) ? cnt[i] : 0;
  s[t] = v;
  __syncthreads();
  for (int off = 1; off < 1024; off <<= 1){
    int a = (t >= off) ? s[t-off] : 0;
    __syncthreads();
    s[t] += a;
    __syncthreads();
  }
  if (i < N) offs[i] = s[t] - v;          // block-local exclusive
  if (t == 1023) blksum[blockIdx.x] = s[t];
}

__global__ void k_scan2(int* __restrict__ blksum, int nblk){
  if (threadIdx.x == 0 && blockIdx.x == 0){
    int run = 0;
    for (int i = 0; i < nblk; ++i){ int t = blksum[i]; blksum[i] = run; run += t; }
  }
}

__global__ void k_scan3(int* __restrict__ offs, const int* __restrict__ blksum, int N, int E){
  int i = blockIdx.x*256 + threadIdx.x;
  if (i < N) offs[i] += blksum[i >> 10];
  else if (i == N) offs[N] = E;
}

__global__ void k_fill(const int* __restrict__ src, const int* __restrict__ dst,
                       const float* __restrict__ base_w, const float* __restrict__ dist,
                       const float* __restrict__ rho,
                       const int* __restrict__ offs, int* __restrict__ fill,
                       float4* __restrict__ csr4, int E){
  int i = blockIdx.x*256 + threadIdx.x;
  if (i < E){
    int d = dst[i];
    int p = offs[d] + atomicAdd(&fill[d], 1);
    int s = src[i];
    csr4[p] = make_float4(__int_as_float(s), dist[i], base_w[i]*rho[s], 0.f);
  }
}

// ---------------- encoder layer 1 (split-K x4): part = X @ W1 -------------
// X: (N,C), W1: (C,64). 128 rows/block, 128 threads (2 waves), BK=32.
// Per-thread 8 rows x 8 cols (64 acc): per k = 2 X b128 + 2 W b128 -> 64 FMA
// (LDS:VALU = 48:128 per wave -> VALUBusy ceiling ~66% vs 44% before).
// W staged via global_load_lds (linear [32][64], zero staging VGPRs);
// X reg-prefetched + transposed into [k][row] stride 132 (conflict-free).
// Split-K x4 -> 1564 blocks = 6 blk/CU (12 waves/CU), LDS 24.5KB/block.
#define KSEG 252
__global__ __launch_bounds__(128) void k_enc1(const float* __restrict__ X,
                                              const float* __restrict__ W1,
                                              float* __restrict__ pA,
                                              float* __restrict__ pB,
                                              int N, int C){
  __shared__ float Xs[32*132];
  __shared__ float Ws[32*64];
  int tid = threadIdx.x;
  int row0 = blockIdx.x*128;
  int seg = blockIdx.y;
  int kbeg = seg*KSEG;
  int kend = min(kbeg + KSEG, C);
  float* part = (seg < 2 ? pA : pB) + (size_t)(seg & 1)*N*64;

  int tx8 = (tid & 7)*8;
  int ty8 = (tid >> 3)*8;

  bool rok = (row0 + tid) < N;
  const float* xrow = X + (size_t)(rok ? (row0 + tid) : 0)*C;

  // W gload_lds mapping: chunk = (wave)*4 + i, elem = chunk*256 + lane*4
  int chunk0 = (tid >> 6)*4;
  int lane4  = (tid & 63)*4;

  float4 xr[8];
  auto loadX = [&](int k0){
    #pragma unroll
    for (int j = 0; j < 8; ++j){
      int k = k0 + j*4;
      xr[j] = (rok && k < kend) ? *(const float4*)(xrow + k) : make_float4(0.f,0.f,0.f,0.f);
    }
  };
  auto issueW = [&](int k0){
    #pragma unroll
    for (int i = 0; i < 4; ++i){
      int elem = (chunk0 + i)*256 + lane4;
      int kk = elem >> 6, c4 = elem & 63;
      int k = min(k0 + kk, C-1);          // clamp: pad region multiplied by Xs zeros
      gload_lds16(W1 + (size_t)k*64 + c4, Ws + (chunk0 + i)*256);
    }
  };
  auto storeX = [&](){
    #pragma unroll
    for (int j = 0; j < 8; ++j){
      #pragma unroll
      for (int e = 0; e < 4; ++e)
        Xs[(j*4 + e)*132 + tid] = (&xr[j].x)[e];
    }
  };

  float acc[8][8];
  #pragma unroll
  for (int p = 0; p < 8; ++p)
    #pragma unroll
    for (int c = 0; c < 8; ++c) acc[p][c] = 0.f;

  loadX(kbeg); issueW(kbeg); storeX();
  __syncthreads();

  const int nt = 8;                      // ceil(252/32) == ceil(244/32) == 8
  for (int t = 0; t < nt; ++t){
    if (t+1 < nt) loadX(kbeg + (t+1)*32);   // global->reg, lands during compute
    #pragma unroll 2
    for (int k = 0; k < 32; ++k){
      float4 xa = *(const float4*)(Xs + k*132 + ty8);
      float4 xb = *(const float4*)(Xs + k*132 + ty8 + 4);
      float4 wa = *(const float4*)(Ws + k*64 + tx8);
      float4 wb = *(const float4*)(Ws + k*64 + tx8 + 4);
      float xv[8] = {xa.x,xa.y,xa.z,xa.w,xb.x,xb.y,xb.z,xb.w};
      float wv[8] = {wa.x,wa.y,wa.z,wa.w,wb.x,wb.y,wb.z,wb.w};
      #pragma unroll
      for (int p = 0; p < 8; ++p)
        #pragma unroll
        for (int c = 0; c < 8; ++c)
          acc[p][c] = fmaf(xv[p], wv[c], acc[p][c]);
    }
    __syncthreads();
    if (t+1 < nt){
      issueW(kbeg + (t+1)*32);
      storeX();
      __syncthreads();                   // drains W vmcnt; covered by 5 other blocks/CU
    }
  }

  #pragma unroll
  for (int p = 0; p < 8; ++p){
    int row = row0 + ty8 + p;
    if (row < N){
      float* op = part + (size_t)row*64 + tx8;
      *(float4*)(op)     = make_float4(acc[p][0], acc[p][1], acc[p][2], acc[p][3]);
      *(float4*)(op + 4) = make_float4(acc[p][4], acc[p][5], acc[p][6], acc[p][7]);
    }
  }
}

// fixup: h1 = relu(p0+p1+p2+p3 + b1)
__global__ __launch_bounds__(256) void k_encfix4(const float* __restrict__ p0,
                                                 const float* __restrict__ p1,
                                                 const float* __restrict__ p2,
                                                 const float* __restrict__ p3,
                                                 const float* __restrict__ b1,
                                                 float* __restrict__ h1, int total4){
  int i = blockIdx.x*256 + threadIdx.x;
  if (i < total4){
    float4 a = *(const float4*)(p0 + (size_t)i*4);
    float4 b = *(const float4*)(p1 + (size_t)i*4);
    float4 c = *(const float4*)(p2 + (size_t)i*4);
    float4 d = *(const float4*)(p3 + (size_t)i*4);
    float4 bv = *(const float4*)(b1 + ((i*4) & 63));
    float4 o;
    o.x = fmaxf(a.x + b.x + c.x + d.x + bv.x, 0.f);
    o.y = fmaxf(a.y + b.y + c.y + d.y + bv.y, 0.f);
    o.z = fmaxf(a.z + b.z + c.z + d.z + bv.z, 0.f);
    o.w = fmaxf(a.w + b.w + c.w + d.w + bv.w, 0.f);
    *(float4*)(h1 + (size_t)i*4) = o;
  }
}

// ---------------- small GEMM: Y = epi(X(N,64) @ W(64,CO) + bias) ----------
// EPI: 0=none 1=relu 2=layernorm(residual HP) 3=softplus
template<int CO, int EPI>
__global__ __launch_bounds__(256) void k_small_gemm(
    const float* __restrict__ X, int xstride, int xoff,
    const float* __restrict__ W, const float* __restrict__ bias,
    float* __restrict__ Y, int ystride, int yoff,
    const float* __restrict__ HP, int hpstride, int hpoff,
    const float* __restrict__ lng, const float* __restrict__ lnb,
    int nrows){
  constexpr int CPT = CO/16;
  __shared__ float Xs[64*68];
  __shared__ float Ws[64*CO];
  int tid = threadIdx.x;
  int row0 = blockIdx.x*64;
  for (int q = tid; q < 1024; q += 256){
    int r = q >> 4, kq = q & 15;
    int row = row0 + r;
    float4 v = make_float4(0.f,0.f,0.f,0.f);
    if (row < nrows) v = *(const float4*)(X + (size_t)row*xstride + xoff + kq*4);
    *(float4*)(Xs + r*68 + kq*4) = v;
  }
  for (int i = tid; i < 64*CO; i += 256) Ws[i] = W[i];
  __syncthreads();
  int tx = tid & 15, ty = tid >> 4;
  int colbase = tx*CPT;
  float acc[4][CPT];
  #pragma unroll
  for (int p = 0; p < 4; ++p)
    #pragma unroll
    for (int c = 0; c < CPT; ++c) acc[p][c] = 0.f;
  #pragma unroll 8
  for (int k = 0; k < 64; ++k){
    float wv[CPT];
    if constexpr (CPT == 4){
      float4 t = *(const float4*)(Ws + k*CO + colbase);
      wv[0]=t.x; wv[1]=t.y; wv[2]=t.z; wv[3]=t.w;
    } else {
      float2 t = *(const float2*)(Ws + k*CO + colbase);
      wv[0]=t.x; wv[1]=t.y;
    }
    #pragma unroll
    for (int p = 0; p < 4; ++p){
      float x = Xs[(ty*4 + p)*68 + k];
      #pragma unroll
      for (int c = 0; c < CPT; ++c) acc[p][c] = fmaf(x, wv[c], acc[p][c]);
    }
  }
  float bv[CPT];
  #pragma unroll
  for (int c = 0; c < CPT; ++c) bv[c] = bias ? bias[colbase + c] : 0.f;

  if constexpr (EPI == 2){
    // layernorm(h + u)*g + b ; CO must be 64
    float lg[4], lb[4];
    #pragma unroll
    for (int c = 0; c < 4; ++c){ lg[c] = lng[colbase + c]; lb[c] = lnb[colbase + c]; }
    float hn[4][4];
    #pragma unroll
    for (int p = 0; p < 4; ++p){
      int row = row0 + ty*4 + p;
      #pragma unroll
      for (int c = 0; c < 4; ++c){
        float h = (row < nrows) ? HP[(size_t)row*hpstride + hpoff + colbase + c] : 0.f;
        hn[p][c] = h + acc[p][c] + bv[c];
      }
    }
    float rs[4], vs[4];
    #pragma unroll
    for (int p = 0; p < 4; ++p) rs[p] = hn[p][0]+hn[p][1]+hn[p][2]+hn[p][3];
    #pragma unroll
    for (int m = 8; m >= 1; m >>= 1)
      #pragma unroll
      for (int p = 0; p < 4; ++p) rs[p] += __shfl_xor(rs[p], m, 64);
    float mean[4], inv[4];
    #pragma unroll
    for (int p = 0; p < 4; ++p) mean[p] = rs[p] * 0.015625f;
    #pragma unroll
    for (int p = 0; p < 4; ++p){
      float d0 = hn[p][0]-mean[p], d1 = hn[p][1]-mean[p];
      float d2 = hn[p][2]-mean[p], d3 = hn[p][3]-mean[p];
      vs[p] = d0*d0 + d1*d1 + d2*d2 + d3*d3;
    }
    #pragma unroll
    for (int m = 8; m >= 1; m >>= 1)
      #pragma unroll
      for (int p = 0; p < 4; ++p) vs[p] += __shfl_xor(vs[p], m, 64);
    #pragma unroll
    for (int p = 0; p < 4; ++p) inv[p] = 1.f / sqrtf(vs[p]*0.015625f + 1e-5f);
    #pragma unroll
    for (int p = 0; p < 4; ++p){
      int row = row0 + ty*4 + p;
      if (row < nrows){
        float o0 = fmaf(lg[0], (hn[p][0]-mean[p])*inv[p], lb[0]);
        float o1 = fmaf(lg[1], (hn[p][1]-mean[p])*inv[p], lb[1]);
        float o2 = fmaf(lg[2], (hn[p][2]-mean[p])*inv[p], lb[2]);
        float o3 = fmaf(lg[3], (hn[p][3]-mean[p])*inv[p], lb[3]);
        *(float4*)(Y + (size_t)row*ystride + yoff + colbase) = make_float4(o0,o1,o2,o3);
      }
    }
  } else {
    #pragma unroll
    for (int p = 0; p < 4; ++p){
      int row = row0 + ty*4 + p;
      if (row < nrows){
        float o[CPT];
        #pragma unroll
        for (int c = 0; c < CPT; ++c){
          float v = acc[p][c] + bv[c];
          if constexpr (EPI == 1) v = fmaxf(v, 0.f);
          if constexpr (EPI == 3) v = softplusf_dev(v);
          o[c] = v;
        }
        if constexpr (CPT == 4)
          *(float4*)(Y + (size_t)row*ystride + yoff + colbase) = make_float4(o[0],o[1],o[2],o[3]);
        else
          *(float2*)(Y + (size_t)row*ystride + yoff + colbase) = make_float2(o[0],o[1]);
      }
    }
  }
}

// ---------------- fused gate projections: a = h@GW[0:64], b = h@GW[64:128] -
// One pass over h producing both outputs (CO=128 concat).
__global__ __launch_bounds__(256) void k_gate(
    const float* __restrict__ X, int xstride, int xoff,
    const float* __restrict__ GW1,
    float* __restrict__ Ya,            // stride 128, off 0 (pk.a)
    float* __restrict__ Yb,            // stride 64 (bbuf)
    int nrows){
  __shared__ float Xs[64*68];
  __shared__ float Ws[64*128];
  int tid = threadIdx.x;
  int row0 = blockIdx.x*64;
  for (int q = tid; q < 1024; q += 256){
    int r = q >> 4, kq = q & 15;
    int row = row0 + r;
    float4 v = make_float4(0.f,0.f,0.f,0.f);
    if (row < nrows) v = *(const float4*)(X + (size_t)row*xstride + xoff + kq*4);
    *(float4*)(Xs + r*68 + kq*4) = v;
  }
  for (int q = tid; q < 2048; q += 256){
    int idx = q*4;
    int k = idx >> 7, c = idx & 127;
    const float* src = (c < 64) ? (GW1 + (size_t)k*64 + c)
                                : (GW1 + (size_t)(64 + k)*64 + (c - 64));
    *(float4*)(Ws + idx) = *(const float4*)src;
  }
  __syncthreads();
  int tx = tid & 15, ty = tid >> 4;
  int colbase = tx*8;
  float acc[4][8];
  #pragma unroll
  for (int p = 0; p < 4; ++p)
    #pragma unroll
    for (int c = 0; c < 8; ++c) acc[p][c] = 0.f;
  #pragma unroll 4
  for (int k = 0; k < 64; ++k){
    float4 wa = *(const float4*)(Ws + k*128 + colbase);
    float4 wb = *(const float4*)(Ws + k*128 + colbase + 4);
    float wv[8] = {wa.x,wa.y,wa.z,wa.w,wb.x,wb.y,wb.z,wb.w};
    #pragma unroll
    for (int p = 0; p < 4; ++p){
      float x = Xs[(ty*4 + p)*68 + k];
      #pragma unroll
      for (int c = 0; c < 8; ++c) acc[p][c] = fmaf(x, wv[c], acc[p][c]);
    }
  }
  #pragma unroll
  for (int p = 0; p < 4; ++p){
    int row = row0 + ty*4 + p;
    if (row < nrows){
      if (tx < 8){
        float* op = Ya + (size_t)row*128 + colbase;
        *(float4*)(op)     = make_float4(acc[p][0],acc[p][1],acc[p][2],acc[p][3]);
        *(float4*)(op + 4) = make_float4(acc[p][4],acc[p][5],acc[p][6],acc[p][7]);
      } else {
        float* op = Yb + (size_t)row*64 + (colbase - 64);
        *(float4*)(op)     = make_float4(acc[p][0],acc[p][1],acc[p][2],acc[p][3]);
        *(float4*)(op + 4) = make_float4(acc[p][4],acc[p][5],acc[p][6],acc[p][7]);
      }
    }
  }
}

// ---------------- aggregation: neigh = (sum_e w*h[src]) / (sum_e w + eps) --
// wave per node; lane = channel. pk row: [a(64) | h(64)].
// 2-edge unroll: two independent shfl-reduce chains in flight.
__global__ __launch_bounds__(256) void k_agg(
    const float* __restrict__ pk, const float* __restrict__ bbuf,
    const float* __restrict__ rho, const float4* __restrict__ csr4,
    const int* __restrict__ offs,
    const float* __restrict__ gw1, const float* __restrict__ gb1,
    const float* __restrict__ gw2, const float* __restrict__ gb2,
    float* __restrict__ neigh, int N){
  int tid = threadIdx.x;
  int j = tid & 63;
  int v = blockIdx.x*4 + (tid >> 6);
  if (v >= N) return;
  float gcj  = gw1[128*64 + j];      // dist row of gate_w1
  float gw2j = gw2[j];
  float bb   = bbuf[(size_t)v*64 + j] + gb1[j];
  float gb2v = gb2[0];
  float rhov = rho[v];
  int beg = offs[v], end = offs[v+1];
  float acc = 0.f, deg = 0.f;
  int i = beg;
  for (; i + 1 < end; i += 2){
    float4 e0 = csr4[i];
    float4 e1 = csr4[i+1];
    int s0 = __float_as_int(e0.x);
    int s1 = __float_as_int(e1.x);
    const float* p0 = pk + (size_t)s0*128;
    const float* p1 = pk + (size_t)s1*128;
    float av0 = p0[j], hv0 = p0[64 + j];
    float av1 = p1[j], hv1 = p1[64 + j];
    float t0 = fmaxf(fmaf(e0.y, gcj, av0 + bb), 0.f) * gw2j;
    float t1 = fmaxf(fmaf(e1.y, gcj, av1 + bb), 0.f) * gw2j;
    #pragma unroll
    for (int m = 32; m >= 1; m >>= 1){
      t0 += __shfl_xor(t0, m, 64);
      t1 += __shfl_xor(t1, m, 64);
    }
    float g0 = sigmoidf_fast(t0 + gb2v);
    float g1 = sigmoidf_fast(t1 + gb2v);
    float w0 = g0 * e0.z * rhov;
    float w1 = g1 * e1.z * rhov;
    acc = fmaf(w0, hv0, acc);
    acc = fmaf(w1, hv1, acc);
    deg += w0 + w1;
  }
  if (i < end){
    float4 e = csr4[i];
    int s = __float_as_int(e.x);
    const float* ps = pk + (size_t)s*128;
    float av = ps[j];
    float hv = ps[64 + j];
    float t = fmaxf(fmaf(e.y, gcj, av + bb), 0.f) * gw2j;
    #pragma unroll
    for (int m = 32; m >= 1; m >>= 1) t += __shfl_xor(t, m, 64);
    float gate = sigmoidf_fast(t + gb2v);
    float wgt = gate * e.z * rhov;
    acc = fmaf(wgt, hv, acc);
    deg += wgt;
  }
  neigh[(size_t)v*64 + j] = acc * __builtin_amdgcn_rcpf(deg + 1e-8f);
}

// ---------------- final: mu = exp(clip(loglib + log(U@W^T) + alpha + bcorr))
__global__ __launch_bounds__(256) void k_final(
    const float* __restrict__ U, const float* __restrict__ WT,
    const float* __restrict__ alpha, const float* __restrict__ bcorr,
    const float* __restrict__ loglib, const int* __restrict__ sid,
    float* __restrict__ out, int N, int C, int npb){
  int c = blockIdx.x*256 + threadIdx.x;
  bool active = (c < C);
  int cc = active ? c : (C-1);
  float wreg[32];
  #pragma unroll
  for (int k = 0; k < 32; ++k) wreg[k] = WT[k*C + cc];
  float al = alpha[cc];
  int n0 = blockIdx.y * npb;
  int n1 = min(n0 + npb, N);
  for (int n = n0; n < n1; ++n){
    int sd   = sid[n];        // wave-uniform -> scalar loads
    float ll = loglib[n];
    const float* Ur = U + (size_t)n*32;
    float dot = 0.f;
    #pragma unroll
    for (int k = 0; k < 32; ++k) dot = fmaf(Ur[k], wreg[k], dot);
    float lm = ll + __logf(fmaxf(dot, 1e-8f)) + al + bcorr[sd*C + cc];
    lm = fminf(fmaxf(lm, -20.f), 20.f);
    if (active) out[(size_t)n*C + c] = __expf(lm);
  }
}

// ---------------------------------------------------------------------------
extern "C" void kernel_launch(void* const* d_in, const int* in_sizes, int n_in,
                              void* d_out, int out_size, void* d_ws, size_t ws_size,
                              hipStream_t stream){
  const float* x_common = (const float*)d_in[0];
  const int*   src      = (const int*)  d_in[1];
  const int*   dst      = (const int*)  d_in[2];
  const float* base_w   = (const float*)d_in[3];
  const float* dist     = (const float*)d_in[4];
  const float* lib      = (const float*)d_in[5];
  const int*   sid      = (const int*)  d_in[6];
  const float* enc_w1   = (const float*)d_in[7];
  const float* enc_b1   = (const float*)d_in[8];
  const float* enc_w2   = (const float*)d_in[9];
  const float* enc_b2   = (const float*)d_in[10];
  const float* upd_w1   = (const float*)d_in[11];
  const float* upd_b1   = (const float*)d_in[12];
  const float* upd_w2   = (const float*)d_in[13];
  const float* upd_b2   = (const float*)d_in[14];
  const float* ln_g     = (const float*)d_in[15];
  const float* ln_b     = (const float*)d_in[16];
  const float* gate_w1  = (const float*)d_in[17];
  const float* gate_b1  = (const float*)d_in[18];
  const float* gate_w2  = (const float*)d_in[19];
  const float* gate_b2  = (const float*)d_in[20];
  const float* rho_raw  = (const float*)d_in[21];
  const float* toU_w    = (const float*)d_in[22];
  const float* toU_b    = (const float*)d_in[23];
  const float* W_raw    = (const float*)d_in[24];
  const float* alpha    = (const float*)d_in[25];
  const float* P        = (const float*)d_in[26];
  const float* Q        = (const float*)d_in[27];

  const int N = in_sizes[5];            // 50000
  const int E = in_sizes[1];            // 800000
  const int C = in_sizes[25];           // 1000
  const int K = in_sizes[23];           // 32
  const int R = in_sizes[27] / C;       // 16
  const int S = in_sizes[26] / R;       // 8
  const int L = in_sizes[15] / 64;      // 2

  float* w = (float*)d_ws;
  size_t o = 0;
  auto alloc = [&](size_t n)->float*{ float* p = w + o; o += (n + 63) & ~((size_t)63); return p; };
  float*  pkA   = alloc((size_t)N*128);   // [a | h] packed per node
  float*  pkB   = alloc((size_t)N*128);
  float*  bbuf  = alloc((size_t)N*64);
  float*  tbuf  = alloc((size_t)N*64);    // h1, later update-MLP hidden
  float*  neigh = alloc((size_t)N*64);
  float*  Ubuf  = alloc((size_t)N*32);
  float*  rho   = alloc((size_t)N);
  float*  loglib= alloc((size_t)N);
  float*  WT    = alloc((size_t)K*C);
  float*  bcorr = alloc((size_t)S*C);
  float4* csr4  = (float4*)alloc((size_t)E*4);
  int*    cnt   = (int*)alloc((size_t)N);
  int*    offs  = (int*)alloc((size_t)N + 64);
  int*    fillc = (int*)alloc((size_t)N);
  int*    blksum= (int*)alloc(256);

  hipMemsetAsync(cnt,   0, sizeof(int)*(size_t)N, stream);
  hipMemsetAsync(fillc, 0, sizeof(int)*(size_t)N, stream);

  // prep
  k_prep_node<<<(N+255)/256,256,0,stream>>>(rho_raw, lib, rho, loglib, N);
  k_prep_W<<<(K*C+255)/256,256,0,stream>>>(W_raw, WT, C, K);
  k_prep_bcorr<<<1,256,0,stream>>>(P, Q, bcorr, S, R, C);

  // CSR by dst
  k_hist<<<(E+255)/256,256,0,stream>>>(dst, cnt, E);
  int nblk = (N+1023)/1024;
  k_scan1<<<nblk,1024,0,stream>>>(cnt, offs, blksum, N);
  k_scan2<<<1,64,0,stream>>>(blksum, nblk);
  k_scan3<<<(N+256)/256,256,0,stream>>>(offs, blksum, N, E);
  k_fill<<<(E+255)/256,256,0,stream>>>(src, dst, base_w, dist, rho, offs, fillc, csr4, E);

  // encoder layer 1: split-K x4 (partials in pkA/pkB), fixup into tbuf
  dim3 eg((N + 127)/128, 4);
  k_enc1<<<eg,128,0,stream>>>(x_common, enc_w1, pkA, pkB, N, C);
  int total4 = (N*64)/4;
  k_encfix4<<<(total4+255)/256,256,0,stream>>>(pkA, pkA + (size_t)N*64,
                                               pkB, pkB + (size_t)N*64,
                                               enc_b1, tbuf, total4);

  int gsm = (N+63)/64;
  // h = relu(h1@enc_w2 + b2) -> pkA.h
  k_small_gemm<64,1><<<gsm,256,0,stream>>>(tbuf,64,0, enc_w2, enc_b2, pkA,128,64,
                                           nullptr,0,0, nullptr,nullptr, N);
  // fused gate projections: a -> pkA.a, b -> bbuf
  k_gate<<<gsm,256,0,stream>>>(pkA,128,64, gate_w1, pkA, bbuf, N);

  float* cur = pkA; float* nxt = pkB;
  for (int l = 0; l < L; ++l){
    k_agg<<<(N+3)/4,256,0,stream>>>(cur, bbuf, rho, csr4, offs,
                                    gate_w1, gate_b1, gate_w2, gate_b2, neigh, N);
    k_small_gemm<64,1><<<gsm,256,0,stream>>>(neigh,64,0, upd_w1 + (size_t)l*64*64, upd_b1 + l*64,
                                             tbuf,64,0, nullptr,0,0, nullptr,nullptr, N);
    k_small_gemm<64,2><<<gsm,256,0,stream>>>(tbuf,64,0, upd_w2 + (size_t)l*64*64, upd_b2 + l*64,
                                             nxt,128,64, cur,128,64, ln_g + l*64, ln_b + l*64, N);
    if (l + 1 < L){
      k_gate<<<gsm,256,0,stream>>>(nxt,128,64, gate_w1, nxt, bbuf, N);
    }
    float* t = cur; cur = nxt; nxt = t;
  }

  // U = softplus(h @ toU_w + toU_b)
  k_small_gemm<32,3><<<gsm,256,0,stream>>>(cur,128,64, toU_w, toU_b, Ubuf,32,0,
                                           nullptr,0,0, nullptr,nullptr, N);

  // mu
  dim3 fg((C+255)/256, (N+63)/64);
  k_final<<<fg,256,0,stream>>>(Ubuf, WT, alpha, bcorr, loglib, sid, (float*)d_out, N, C, 64);
}